// Round 1
// baseline (324.881 us; speedup 1.0000x reference)
//
#include <hip/hip_runtime.h>

#define DIM 32

// Zero the output accumulator and the degree array (both re-poisoned to 0xAA
// by the harness before every timed launch).
__global__ void zero_kernel(float* __restrict__ out, float* __restrict__ deg,
                            int n_out, int n_nodes) {
    int stride = gridDim.x * blockDim.x;
    for (int t = blockIdx.x * blockDim.x + threadIdx.x; t < n_out; t += stride)
        out[t] = 0.0f;
    for (int t = blockIdx.x * blockDim.x + threadIdx.x; t < n_nodes; t += stride)
        deg[t] = 0.0f;
}

// One thread per (edge, feature). 32 consecutive threads share one edge:
// they read a contiguous 128B row of x (coalesced) and atomically add a
// contiguous 128B row of out. Lane f==0 also bumps the degree counter.
__global__ void scatter_kernel(const float* __restrict__ x,
                               const int* __restrict__ src,
                               const int* __restrict__ dst,
                               float* __restrict__ out,
                               float* __restrict__ deg,
                               int n_edges) {
    long long t = (long long)blockIdx.x * blockDim.x + threadIdx.x;
    long long total = (long long)n_edges * DIM;
    if (t >= total) return;
    int e = (int)(t >> 5);
    int f = (int)(t & 31);
    int s = src[e];
    int d = dst[e];
    float v = x[(long long)s * DIM + f];
    atomicAdd(&out[(long long)d * DIM + f], v);
    if (f == 0) atomicAdd(&deg[d], 1.0f);
}

// out[n, f] /= max(deg[n], 1)
__global__ void div_kernel(float* __restrict__ out, const float* __restrict__ deg,
                           int n_out) {
    int t = blockIdx.x * blockDim.x + threadIdx.x;
    if (t >= n_out) return;
    int n = t >> 5;  // DIM == 32
    out[t] = out[t] / fmaxf(deg[n], 1.0f);
}

extern "C" void kernel_launch(void* const* d_in, const int* in_sizes, int n_in,
                              void* d_out, int out_size, void* d_ws, size_t ws_size,
                              hipStream_t stream) {
    const float* x   = (const float*)d_in[0];
    const int*   src = (const int*)d_in[1];
    const int*   dst = (const int*)d_in[2];
    float* out = (float*)d_out;
    float* deg = (float*)d_ws;   // n_nodes floats of scratch

    int n_nodes = in_sizes[0] / DIM;
    int n_edges = in_sizes[1];
    int n_out   = out_size;      // n_nodes * DIM

    // 1) zero accumulators
    {
        int threads = 256;
        int blocks  = (n_out + threads - 1) / threads;  // covers n_nodes too
        zero_kernel<<<blocks, threads, 0, stream>>>(out, deg, n_out, n_nodes);
    }
    // 2) edge scatter-add
    {
        long long total = (long long)n_edges * DIM;
        int threads = 256;
        int blocks  = (int)((total + threads - 1) / threads);
        scatter_kernel<<<blocks, threads, 0, stream>>>(x, src, dst, out, deg, n_edges);
    }
    // 3) divide by degree
    {
        int threads = 256;
        int blocks  = (n_out + threads - 1) / threads;
        div_kernel<<<blocks, threads, 0, stream>>>(out, deg, n_out);
    }
}